// Round 4
// baseline (3811.543 us; speedup 1.0000x reference)
//
#include <hip/hip_runtime.h>

// Problem constants (fixed by the reference)
constexpr int Bc = 64;      // batch
constexpr int Tc = 2048;    // time steps
constexpr int Ic = 3;       // input dim
constexpr int Hc = 512;     // hidden
constexpr float AL = 0.2f;  // ALPHA
constexpr float NS = 0.05f; // NOISE_STD
constexpr int NSL = 4;      // slices (blocks) per batch
constexpr int HS  = Hc / NSL; // 128 h per slice
constexpr int PAD = 132;    // padded slice stride in LDS

// d_ws layout:
//   [0, 1MB)          WT fp32 [512][512]  (WT[k][h] = w_rec[h][k])
//   [1MB, 1MB+512KB)  rbuf u64 [64 batches][2 parity][512 h] = {tag<<32 | f32bits}
// ---------------------------------------------------------------------------
__global__ void prep_wt(const float* __restrict__ m, const float* __restrict__ n,
                        const float* __restrict__ rn, float* __restrict__ WT, int R) {
    int id = blockIdx.x * 256 + threadIdx.x;
    if (id >= Hc * Hc) return;
    int k = id >> 9;
    int h = id & (Hc - 1);
    float acc = rn[h * Hc + k];
    for (int r = 0; r < R; ++r)
        acc = fmaf(m[h * R + r], n[k * R + r] * (1.0f / Hc), acc);
    WT[id] = acc;
}

// L2-coherent poll load: bypass L1 (sc0), hit the XCD-shared L2.
__device__ __forceinline__ unsigned long long ld_sc0(const unsigned long long* p) {
    unsigned long long v;
    asm volatile("global_load_dwordx2 %0, %1, off sc0\n\t"
                 "s_waitcnt vmcnt(0)"
                 : "=v"(v) : "v"(p) : "memory");
    return v;
}

// --- macro machinery: 32 NAMED float4s (pure SSA, no alloca -> no scratch) ---
#define REPEAT32(F) F(0) F(1) F(2) F(3) F(4) F(5) F(6) F(7) \
                    F(8) F(9) F(10) F(11) F(12) F(13) F(14) F(15) \
                    F(16) F(17) F(18) F(19) F(20) F(21) F(22) F(23) \
                    F(24) F(25) F(26) F(27) F(28) F(29) F(30) F(31)

#define WDECL(i) float4 w##i;
#define WLOAD(i) w##i = make_float4(Wp[(size_t)(4*(i)+0) * Hc], \
                                    Wp[(size_t)(4*(i)+1) * Hc], \
                                    Wp[(size_t)(4*(i)+2) * Hc], \
                                    Wp[(size_t)(4*(i)+3) * Hc]);
#define WPIN(i)  asm volatile("" : "+v"(w##i.x), "+v"(w##i.y), "+v"(w##i.z), "+v"(w##i.w));
#define WFMA(i)  { const float4 rv##i = *(const float4*)(rg + 4*(i)); \
                   acc0 = fmaf(w##i.x, rv##i.x, acc0); \
                   acc1 = fmaf(w##i.y, rv##i.y, acc1); \
                   acc2 = fmaf(w##i.z, rv##i.z, acc2); \
                   acc3 = fmaf(w##i.w, rv##i.w, acc3); }

// ---------------------------------------------------------------------------
// 4 blocks per batch, h-split. W slice in 32 named float4 registers/thread.
// Thread layout: h_local = tid>>2 (0..127), kg = tid&3 (k-group of 128).
// Quad shfl_xor reduces the 4 k-partials -> one barrier per step.
// Cross-block r exchange: {tag,val} u64, agent-scope publish, hybrid
// sc0(L2)/agent(MALL) polling. Parity-double-buffered r in LDS.
// ---------------------------------------------------------------------------
__launch_bounds__(512, 2)   // 2 waves/EU = 8 waves/CU = 1 block -> VGPR cap 256
__global__ void rnn4r(const float* __restrict__ input, const float* __restrict__ noise,
                      const float* __restrict__ w_i, const float* __restrict__ s_i,
                      const float* __restrict__ WT, const float* __restrict__ w_o,
                      const float* __restrict__ s_o, const float* __restrict__ h0,
                      float* __restrict__ out, unsigned long long* __restrict__ rbuf) {
    __shared__ float rp[2][NSL * PAD];   // parity-double-buffered r (padded slices)
    __shared__ float red[8];             // output reduce scratch

    const int tid   = threadIdx.x;
    const int s     = blockIdx.x >> 6;   // slice 0..3 (owns h in [128s,128s+128))
    const int b     = blockIdx.x & 63;   // batch
    const int hl    = tid >> 2;          // local h 0..127
    const int kg    = tid & 3;           // k-group (k in [128kg,128kg+128))
    const int hbase = s * HS;
    const int hmy   = hbase + hl;

    // --- load + PIN the W slice in named registers: w_i[c] = W[hmy][kg*128+4i+c]
    const float* Wp = WT + (size_t)(kg * 128) * Hc + hmy;
    REPEAT32(WDECL)
    REPEAT32(WLOAD)
    REPEAT32(WPIN)

    const float wo_t = w_o[tid] * s_o[0] * (1.0f / Hc);
    float h = h0[hmy];
    const float wi0 = w_i[0 * Hc + hmy] * s_i[0];
    const float wi1 = w_i[1 * Hc + hmy] * s_i[1];
    const float wi2 = w_i[2 * Hc + hmy] * s_i[2];

    // r_0 into parity-0 buffer (all 512 h, locally computable)
    rp[0][(tid >> 7) * PAD + (tid & 127)] = tanhf(h0[tid]);

    const float* noise_b = noise + (size_t)b * Tc * Hc;
    const float* inp_b   = input + (size_t)b * Tc * Ic;
    unsigned long long* rb_b = rbuf + (size_t)b * 2 * Hc;

    float nz = noise_b[hmy];
    float i0 = inp_b[0], i1 = inp_b[1], i2 = inp_b[2];

    // poller assignment: threads 0..383 <-> the 384 foreign h-words
    const int ft   = tid + ((tid >= hbase) ? 128 : 0);
    const int fpos = (ft >> 7) * PAD + (ft & 127);
    __syncthreads();

    for (int t = 0; t < Tc; ++t) {
        // prefetch next step's drive inputs
        const int tn = (t + 1 < Tc) ? t + 1 : t;
        const float nz_n = noise_b[(size_t)tn * Hc + hmy];
        const float i0n = inp_b[tn * Ic + 0];
        const float i1n = inp_b[tn * Ic + 1];
        const float i2n = inp_b[tn * Ic + 2];

        // --- matvec partial over my k-group (W in regs, r broadcast from LDS) ---
        const float* rg = &rp[t & 1][kg * PAD];
        float acc0 = 0.f, acc1 = 0.f, acc2 = 0.f, acc3 = 0.f;
        REPEAT32(WFMA)
        float y = (acc0 + acc1) + (acc2 + acc3);
        y += __shfl_xor(y, 1, 64);   // quad butterfly: all 4 lanes get the
        y += __shfl_xor(y, 2, 64);   // full k-sum for their h

        // --- state update (redundant across the quad, bitwise identical) ---
        const float di = i0 * wi0 + i1 * wi1 + i2 * wi2;
        h = h + (NS * nz + AL * di) + AL * (y - h);
        const float rv_ = tanhf(h);

        const unsigned want = (unsigned)(t + 1);
        unsigned long long* slot = rb_b + ((size_t)((t + 1) & 1)) * Hc;
        float* wp_ = &rp[(t + 1) & 1][0];

        if (kg == 0) {  // one lane per h publishes + writes own LDS slice
            __hip_atomic_store(&slot[hmy],
                               ((unsigned long long)want << 32) |
                               (unsigned long long)__float_as_uint(rv_),
                               __ATOMIC_RELAXED, __HIP_MEMORY_SCOPE_AGENT);
            wp_[s * PAD + hl] = rv_;
        }

        // --- poll the 384 foreign words: 3x sc0 (L2) : 1x agent (MALL) ---
        if (tid < 384) {
            const unsigned long long* p = &slot[ft];
            unsigned long long v;
            int it = 0;
            for (;;) {
                if ((it & 3) != 3)
                    v = ld_sc0(p);
                else
                    v = __hip_atomic_load(p, __ATOMIC_RELAXED, __HIP_MEMORY_SCOPE_AGENT);
                if ((unsigned)(v >> 32) == want) break;
                ++it;
            }
            wp_[fpos] = __uint_as_float((unsigned)v);
        }
        __syncthreads();   // r_{t+1} complete in rp[(t+1)&1]

        // --- output for step t, rotated across the 4 slice-blocks ---
        if ((t & 3) == s) {
            float p2 = wp_[(tid >> 7) * PAD + (tid & 127)] * wo_t;
            #pragma unroll
            for (int off = 32; off; off >>= 1) p2 += __shfl_xor(p2, off, 64);
            if ((tid & 63) == 0) red[tid >> 6] = p2;
            __syncthreads();
            if (tid == 0)
                out[(size_t)b * Tc + t] = red[0] + red[1] + red[2] + red[3] +
                                          red[4] + red[5] + red[6] + red[7];
        }

        nz = nz_n; i0 = i0n; i1 = i1n; i2 = i2n;
    }
}

// ---------------------------------------------------------------------------
// Fallback (round-1 kernel) if d_ws is too small — safety net.
// ---------------------------------------------------------------------------
__launch_bounds__(512)
__global__ void rnn_scan_fb(const float* __restrict__ input, const float* __restrict__ noise,
                            const float* __restrict__ w_i, const float* __restrict__ s_i,
                            const float* __restrict__ WT, const float* __restrict__ w_o,
                            const float* __restrict__ s_o, const float* __restrict__ h0,
                            float* __restrict__ out) {
    __shared__ float r_lds[Hc];
    __shared__ float pl[4][Hc];
    __shared__ float wi_lds[Ic][Hc];
    __shared__ float red[8];

    const int tid = threadIdx.x;
    const int b   = blockIdx.x;
    const int g   = tid >> 7;
    const int j   = tid & 127;

    for (int i = 0; i < Ic; ++i) wi_lds[i][tid] = w_i[i * Hc + tid] * s_i[i];

    float h = h0[tid];
    float r_cur = tanhf(h);
    const float wo_h = w_o[tid] * s_o[0] * (1.0f / Hc);
    const float* noise_b = noise + (size_t)b * Tc * Hc;
    const float* inp_b   = input + (size_t)b * Tc * Ic;
    float nz = noise_b[tid];
    float i0 = inp_b[0], i1 = inp_b[1], i2 = inp_b[2];
    const float* Wg = WT + (g * 128) * Hc + 4 * j;
    const float* rg = r_lds + g * 128;
    __syncthreads();

    for (int t = 0; t < Tc; ++t) {
        const int tn = (t + 1 < Tc) ? t + 1 : t;
        const float nz_n = noise_b[(size_t)tn * Hc + tid];
        const float i0n = inp_b[tn * Ic + 0];
        const float i1n = inp_b[tn * Ic + 1];
        const float i2n = inp_b[tn * Ic + 2];

        r_lds[tid] = r_cur;
        __syncthreads();
        float a0 = 0.f, a1 = 0.f, a2 = 0.f, a3 = 0.f;
        #pragma unroll 4
        for (int kk = 0; kk < 128; kk += 4) {
            const float4 rv = *(const float4*)(rg + kk);
            const float4 w0 = *(const float4*)(Wg + (kk + 0) * Hc);
            const float4 w1 = *(const float4*)(Wg + (kk + 1) * Hc);
            const float4 w2 = *(const float4*)(Wg + (kk + 2) * Hc);
            const float4 w3 = *(const float4*)(Wg + (kk + 3) * Hc);
            a0 = fmaf(rv.x, w0.x, a0); a0 = fmaf(rv.y, w1.x, a0);
            a0 = fmaf(rv.z, w2.x, a0); a0 = fmaf(rv.w, w3.x, a0);
            a1 = fmaf(rv.x, w0.y, a1); a1 = fmaf(rv.y, w1.y, a1);
            a1 = fmaf(rv.z, w2.y, a1); a1 = fmaf(rv.w, w3.y, a1);
            a2 = fmaf(rv.x, w0.z, a2); a2 = fmaf(rv.y, w1.z, a2);
            a2 = fmaf(rv.z, w2.z, a2); a2 = fmaf(rv.w, w3.z, a2);
            a3 = fmaf(rv.x, w0.w, a3); a3 = fmaf(rv.y, w1.w, a3);
            a3 = fmaf(rv.z, w2.w, a3); a3 = fmaf(rv.w, w3.w, a3);
        }
        *(float4*)&pl[g][4 * j] = make_float4(a0, a1, a2, a3);
        __syncthreads();

        const float y  = pl[0][tid] + pl[1][tid] + pl[2][tid] + pl[3][tid];
        const float di = i0 * wi_lds[0][tid] + i1 * wi_lds[1][tid] + i2 * wi_lds[2][tid];
        h = h + (NS * nz + AL * di) + AL * (y - h);
        r_cur = tanhf(h);

        float p = r_cur * wo_h;
        #pragma unroll
        for (int off = 32; off; off >>= 1) p += __shfl_xor(p, off, 64);
        if ((tid & 63) == 0) red[tid >> 6] = p;
        __syncthreads();
        if (tid == 0)
            out[(size_t)b * Tc + t] = red[0] + red[1] + red[2] + red[3] +
                                      red[4] + red[5] + red[6] + red[7];
        nz = nz_n; i0 = i0n; i1 = i1n; i2 = i2n;
    }
}

extern "C" void kernel_launch(void* const* d_in, const int* in_sizes, int n_in,
                              void* d_out, int out_size, void* d_ws, size_t ws_size,
                              hipStream_t stream) {
    (void)n_in; (void)out_size;
    const float* input     = (const float*)d_in[0];
    const float* noise     = (const float*)d_in[1];
    const float* w_i       = (const float*)d_in[2];
    const float* s_i       = (const float*)d_in[3];
    const float* m_rec     = (const float*)d_in[4];
    const float* n_rec     = (const float*)d_in[5];
    const float* rec_noise = (const float*)d_in[6];
    const float* w_o       = (const float*)d_in[7];
    const float* s_o       = (const float*)d_in[8];
    const float* h0        = (const float*)d_in[9];
    float* out = (float*)d_out;

    const int R = in_sizes[4] / Hc;

    float* WT = (float*)d_ws;
    const size_t wt_bytes = (size_t)Hc * Hc * sizeof(float);
    const size_t rb_bytes = (size_t)Bc * 2 * Hc * sizeof(unsigned long long);

    prep_wt<<<(Hc * Hc + 255) / 256, 256, 0, stream>>>(m_rec, n_rec, rec_noise, WT, R);

    if (ws_size >= wt_bytes + rb_bytes) {
        unsigned long long* rbuf = (unsigned long long*)((char*)d_ws + wt_bytes);
        hipMemsetAsync(rbuf, 0, rb_bytes, stream);  // reset tags every call (replay-safe)
        rnn4r<<<NSL * Bc, 512, 0, stream>>>(input, noise, w_i, s_i, WT, w_o, s_o, h0,
                                            out, rbuf);
    } else {
        rnn_scan_fb<<<Bc, 512, 0, stream>>>(input, noise, w_i, s_i, WT, w_o, s_o, h0, out);
    }
}